// Round 12
// baseline (207.821 us; speedup 1.0000x reference)
//
#include <hip/hip_runtime.h>
#include <hip/hip_bf16.h>

#define N_NODES 50000
#define N_EDGES 800000
#define DIM_IN  128
#define DIM_OUT 64
#define HEADS   4
#define NEG_SLOPE 0.2f
#define NPB 32                                    // nodes per gemm block
#define GEMM_BLOCKS ((N_NODES + NPB - 1) / NPB)   // 1563
#define N_PAD (GEMM_BLOCKS * NPB)                 // 50016
#define XROW 136                                  // LDS row stride (shorts) for x hi/lo
#define LTROW 260                                 // LDS row stride (shorts) for transpose buffer

// binned CSR
#define BIN_SHIFT 5
#define BIN_NODES 32                              // nodes per bin
#define NBINS GEMM_BLOCKS                         // 1563 bins (last bin: 16 nodes)
#define CAP 704                                   // edges per bin region (mean 512, +8.5 sigma; guarded)
#define EPB 16384                                 // edges per binning block
#define ABLOCKS ((N_EDGES + EPB - 1) / EPB)       // 49 binning blocks
#define FAT_GRID (ABLOCKS + GEMM_BLOCKS)          // 1612; binning blocks first (start early)
#define DEGMAX 64                                 // per-node CSR slots (Poisson(16); guarded)

typedef __attribute__((ext_vector_type(8))) short short8;
typedef __attribute__((ext_vector_type(4))) short short4v;
typedef __attribute__((ext_vector_type(4))) float f32x4;

// bf16 helpers (RNE pack, exact shift unpack)
__device__ __forceinline__ unsigned int f2bf(float f) {
    unsigned int u = __float_as_uint(f);
    return (u + 0x7FFFu + ((u >> 16) & 1u)) >> 16;
}
__device__ __forceinline__ float bf2f(unsigned int b) {
    return __uint_as_float(b << 16);
}

// ---------------- Pack W into MFMA B-fragment order, split hi/lo bf16 -------------
__global__ __launch_bounds__(256) void pack_w_kernel(
    const float* __restrict__ W, unsigned short* __restrict__ Wph,
    unsigned short* __restrict__ Wpl)
{
    const int i = blockIdx.x * 256 + threadIdx.x;    // 0..4095
    const int lane = i & 63, nt = (i >> 6) & 3, kc = (i >> 8) & 3, h = (i >> 10) & 3;
    const int col = lane & 15, quad = lane >> 4;
    unsigned short hv[8], lv[8];
#pragma unroll
    for (int j = 0; j < 8; ++j) {
        const int k = kc * 32 + quad * 8 + j;
        const int n = nt * 16 + col;
        const float f = W[h * (DIM_IN * DIM_OUT) + k * DIM_OUT + n];
        const unsigned int hb = f2bf(f);
        hv[j] = (unsigned short)hb;
        lv[j] = (unsigned short)f2bf(f - bf2f(hb));
    }
    *(short8*)(Wph + (size_t)i * 8) = *(short8*)hv;
    *(short8*)(Wpl + (size_t)i * 8) = *(short8*)lv;
}

// ---------------- Fat kernel: binning blocks [0,49) ∥ MFMA-gemm [49,1612) ---------
__global__ __launch_bounds__(256) void fat_kernel(
    const float* __restrict__ x, const unsigned short* __restrict__ Wph,
    const unsigned short* __restrict__ Wpl, const float* __restrict__ a,
    unsigned short* __restrict__ h2, float* __restrict__ s_i, float* __restrict__ s_j,
    const int* __restrict__ ei, int* __restrict__ bin_cursor, unsigned int* __restrict__ binbuf)
{
    __shared__ __align__(16) unsigned char smem[2 * NPB * XROW * 2];  // 17408 B, dual-use
    const int b = blockIdx.x;
    const int t = threadIdx.x;

    if (b < ABLOCKS) {
        // ---- binning role: LDS histogram -> 1 global reserve atomic per bin ----
        int* lcnt = (int*)smem;                           // NBINS ints = 6252 B
        for (int i = t; i < NBINS; i += 256) lcnt[i] = 0;
        __syncthreads();
        const int e_base = b * EPB;
        const int e_end = min(e_base + EPB, N_EDGES);
        // pass 1: histogram of srcs into bins
        for (int e = e_base + t; e < e_end; e += 256)
            atomicAdd(&lcnt[ei[e] >> BIN_SHIFT], 1);
        __syncthreads();
        // reserve: one global atomic per bin; lcnt becomes absolute write cursor
        for (int i = t; i < NBINS; i += 256) {
            const int c = lcnt[i];
            const int old = atomicAdd(&bin_cursor[i], c);
            lcnt[i] = i * CAP + old;
        }
        __syncthreads();
        // pass 2: scatter packed (src_local,dst) pairs into the bin region
        for (int e = e_base + t; e < e_end; e += 256) {
            const int src = ei[e];
            const int dst = ei[N_EDGES + e];
            const int bin = src >> BIN_SHIFT;
            const int pos = atomicAdd(&lcnt[bin], 1);
            if (pos < (bin + 1) * CAP)
                binbuf[pos] = ((unsigned int)(src & (BIN_NODES - 1)) << 16) | (unsigned int)dst;
        }
        return;
    }

    // ---------------- gemm role: h = x @ W via split-bf16 MFMA ------------------
    short* xh = (short*)smem;            // [NPB][XROW]
    short* xl = xh + NPB * XROW;
    const int nb = (b - ABLOCKS) * NPB;

    // stage x tile as hi/lo bf16 (32 nodes x 128 dims)
    {
        const float4* xg = (const float4*)x;
        const int base = nb * (DIM_IN / 4);
        const int limit = N_NODES * (DIM_IN / 4);
#pragma unroll
        for (int r = 0; r < 4; ++r) {
            const int idx = t + 256 * r;              // 0..1023
            const int gi = base + idx;
            float4 v = {0.f, 0.f, 0.f, 0.f};
            if (gi < limit) v = xg[gi];
            const int node = idx >> 5;
            const int dg = (idx & 31) * 4;
            unsigned short hs[4], ls[4];
            const float fv[4] = {v.x, v.y, v.z, v.w};
#pragma unroll
            for (int c = 0; c < 4; ++c) {
                const unsigned int hb = f2bf(fv[c]);
                hs[c] = (unsigned short)hb;
                ls[c] = (unsigned short)f2bf(fv[c] - bf2f(hb));
            }
            *(short4v*)(xh + node * XROW + dg) = *(short4v*)hs;
            *(short4v*)(xl + node * XROW + dg) = *(short4v*)ls;
        }
    }
    __syncthreads();

    const int w = t >> 6;        // wave id == head
    const int lane = t & 63;
    const int col = lane & 15, quad = lane >> 4;

    f32x4 acc[2][4];
#pragma unroll
    for (int mt = 0; mt < 2; ++mt)
#pragma unroll
        for (int nt = 0; nt < 4; ++nt) acc[mt][nt] = (f32x4){0.f, 0.f, 0.f, 0.f};

    const short8* Bh = (const short8*)Wph;
    const short8* Bl = (const short8*)Wpl;
#pragma unroll
    for (int kc = 0; kc < 4; ++kc) {
        const short8 ah0 = *(const short8*)(xh + (0 * 16 + col) * XROW + kc * 32 + quad * 8);
        const short8 al0 = *(const short8*)(xl + (0 * 16 + col) * XROW + kc * 32 + quad * 8);
        const short8 ah1 = *(const short8*)(xh + (1 * 16 + col) * XROW + kc * 32 + quad * 8);
        const short8 al1 = *(const short8*)(xl + (1 * 16 + col) * XROW + kc * 32 + quad * 8);
#pragma unroll
        for (int nt = 0; nt < 4; ++nt) {
            const int fi = ((w * 4 + kc) * 4 + nt) * 64 + lane;
            const short8 bh = Bh[fi];
            const short8 bl = Bl[fi];
            acc[0][nt] = __builtin_amdgcn_mfma_f32_16x16x32_bf16(ah0, bh, acc[0][nt], 0, 0, 0);
            acc[0][nt] = __builtin_amdgcn_mfma_f32_16x16x32_bf16(al0, bh, acc[0][nt], 0, 0, 0);
            acc[0][nt] = __builtin_amdgcn_mfma_f32_16x16x32_bf16(ah0, bl, acc[0][nt], 0, 0, 0);
            acc[1][nt] = __builtin_amdgcn_mfma_f32_16x16x32_bf16(ah1, bh, acc[1][nt], 0, 0, 0);
            acc[1][nt] = __builtin_amdgcn_mfma_f32_16x16x32_bf16(al1, bh, acc[1][nt], 0, 0, 0);
            acc[1][nt] = __builtin_amdgcn_mfma_f32_16x16x32_bf16(ah1, bl, acc[1][nt], 0, 0, 0);
        }
    }

    // scores: lane holds h[node=mt*16+quad*4+r][head=w][o=nt*16+col]
    float aiv[4], ajv[4];
#pragma unroll
    for (int nt = 0; nt < 4; ++nt) {
        aiv[nt] = a[w * (2 * DIM_OUT) + nt * 16 + col];
        ajv[nt] = a[w * (2 * DIM_OUT) + DIM_OUT + nt * 16 + col];
    }
#pragma unroll
    for (int mt = 0; mt < 2; ++mt) {
#pragma unroll
        for (int r = 0; r < 4; ++r) {
            float pi = 0.f, pj = 0.f;
#pragma unroll
            for (int nt = 0; nt < 4; ++nt) {
                pi = fmaf(acc[mt][nt][r], aiv[nt], pi);
                pj = fmaf(acc[mt][nt][r], ajv[nt], pj);
            }
#pragma unroll
            for (int off = 8; off > 0; off >>= 1) {
                pi += __shfl_down(pi, off, 16);
                pj += __shfl_down(pj, off, 16);
            }
            if (col == 0) {
                const int n = nb + mt * 16 + quad * 4 + r;
                s_i[n * HEADS + w] = pi;
                s_j[n * HEADS + w] = pj;
            }
        }
    }
    __syncthreads();   // xh/xl consumed; smem becomes the transpose buffer

    // stage transposed bf16 tile: lt[node][o*4+head] with padded row stride
    short* lt = (short*)smem;
#pragma unroll
    for (int mt = 0; mt < 2; ++mt)
#pragma unroll
        for (int nt = 0; nt < 4; ++nt)
#pragma unroll
            for (int r = 0; r < 4; ++r)
                lt[(mt * 16 + quad * 4 + r) * LTROW + (nt * 16 + col) * 4 + w] =
                    (short)f2bf(acc[mt][nt][r]);
    __syncthreads();

    // dense write-out: 2048 uint2 = 16 KB, coalesced 8B stores
    uint2* hg = (uint2*)(h2 + (size_t)nb * (DIM_OUT * HEADS));
#pragma unroll
    for (int r = 0; r < 8; ++r) {
        const int idx = t + 256 * r;       // 0..2047
        const int node = idx >> 6;
        const int wo = idx & 63;
        hg[idx] = *(const uint2*)(lt + node * LTROW + wo * 4);
    }
}

// ---------------- Fused: one block per bin; LDS CSR build + softmax + aggregate ---
__global__ __launch_bounds__(256) void fused_kernel(
    const int* __restrict__ bin_cursor, const unsigned int* __restrict__ binbuf,
    const float* __restrict__ s_i, const float* __restrict__ s_j,
    const unsigned short* __restrict__ h2, float* __restrict__ out)
{
    __shared__ unsigned short csr[BIN_NODES][DEGMAX];   // 4 KB
    __shared__ int dcnt[BIN_NODES];                     // 128 B
    __shared__ float4 att_s[4][64];                     // 4 KB
    const int bin = blockIdx.x;
    const int t = threadIdx.x;
    const int w = t >> 6;
    const int lane = t & 63;

    if (t < BIN_NODES) dcnt[t] = 0;
    __syncthreads();

    // build 32-node padded CSR in LDS (LDS atomics only)
    const int cnt = min(bin_cursor[bin], CAP);
    const unsigned int* bp = binbuf + (size_t)bin * CAP;
    for (int e = t; e < cnt; e += 256) {
        const unsigned int pr = bp[e];
        const int sl = pr >> 16;
        const int r = atomicAdd(&dcnt[sl], 1);
        if (r < DEGMAX) csr[sl][r] = (unsigned short)(pr & 0xFFFFu);
    }
    __syncthreads();

    // each wave processes nodes w, w+4, ... within the bin
    for (int nl = w; nl < BIN_NODES; nl += 4) {
        const int n = bin * BIN_NODES + nl;
        if (n >= N_NODES) break;
        const int d = min(dcnt[nl], DEGMAX);
        float acc = 0.f;
        if (d > 0) {
            const float4 si = *(const float4*)(s_i + n * HEADS);
            float4 m4 = {-INFINITY, -INFINITY, -INFINITY, -INFINITY};
            float4 cz = {-INFINITY, -INFINITY, -INFINITY, -INFINITY};
            int cdst = 0;
            if (lane < d) {
                cdst = (int)csr[nl][lane];
                const float4 sj = *(const float4*)(s_j + cdst * HEADS);
                float z0 = si.x + sj.x, z1 = si.y + sj.y, z2 = si.z + sj.z, z3 = si.w + sj.w;
                cz.x = z0 >= 0.f ? z0 : NEG_SLOPE * z0;
                cz.y = z1 >= 0.f ? z1 : NEG_SLOPE * z1;
                cz.z = z2 >= 0.f ? z2 : NEG_SLOPE * z2;
                cz.w = z3 >= 0.f ? z3 : NEG_SLOPE * z3;
                m4 = cz;
            }
#pragma unroll
            for (int off = 32; off > 0; off >>= 1) {
                m4.x = fmaxf(m4.x, __shfl_xor(m4.x, off, 64));
                m4.y = fmaxf(m4.y, __shfl_xor(m4.y, off, 64));
                m4.z = fmaxf(m4.z, __shfl_xor(m4.z, off, 64));
                m4.w = fmaxf(m4.w, __shfl_xor(m4.w, off, 64));
            }
            float4 ex = {0.f, 0.f, 0.f, 0.f};
            if (lane < d) {
                ex.x = __expf(cz.x - m4.x);
                ex.y = __expf(cz.y - m4.y);
                ex.z = __expf(cz.z - m4.z);
                ex.w = __expf(cz.w - m4.w);
            }
            float4 sm = ex;
#pragma unroll
            for (int off = 32; off > 0; off >>= 1) {
                sm.x += __shfl_xor(sm.x, off, 64);
                sm.y += __shfl_xor(sm.y, off, 64);
                sm.z += __shfl_xor(sm.z, off, 64);
                sm.w += __shfl_xor(sm.w, off, 64);
            }
            if (lane < d)
                att_s[w][lane] = make_float4(ex.x / sm.x, ex.y / sm.y, ex.z / sm.z, ex.w / sm.w);

            const unsigned short* hbase = h2 + lane * HEADS;
            int e = 0;
            for (; e + 8 <= d; e += 8) {
                uint2 hv[8];
                float4 at[8];
#pragma unroll
                for (int q = 0; q < 8; ++q) {
                    const int dd = (int)csr[nl][e + q];
                    at[q] = att_s[w][e + q];
                    hv[q] = *(const uint2*)(hbase + (size_t)dd * (DIM_OUT * HEADS));
                }
#pragma unroll
                for (int q = 0; q < 8; ++q) {
                    acc += at[q].x * bf2f(hv[q].x & 0xFFFFu) + at[q].y * bf2f(hv[q].x >> 16)
                         + at[q].z * bf2f(hv[q].y & 0xFFFFu) + at[q].w * bf2f(hv[q].y >> 16);
                }
            }
            for (; e + 4 <= d; e += 4) {
                uint2 hv[4];
                float4 at[4];
#pragma unroll
                for (int q = 0; q < 4; ++q) {
                    const int dd = (int)csr[nl][e + q];
                    at[q] = att_s[w][e + q];
                    hv[q] = *(const uint2*)(hbase + (size_t)dd * (DIM_OUT * HEADS));
                }
#pragma unroll
                for (int q = 0; q < 4; ++q) {
                    acc += at[q].x * bf2f(hv[q].x & 0xFFFFu) + at[q].y * bf2f(hv[q].x >> 16)
                         + at[q].z * bf2f(hv[q].y & 0xFFFFu) + at[q].w * bf2f(hv[q].y >> 16);
                }
            }
            for (; e < d; ++e) {
                const int dd = (int)csr[nl][e];
                const float4 a4 = att_s[w][e];
                const uint2 hv = *(const uint2*)(hbase + (size_t)dd * (DIM_OUT * HEADS));
                acc += a4.x * bf2f(hv.x & 0xFFFFu) + a4.y * bf2f(hv.x >> 16)
                     + a4.z * bf2f(hv.y & 0xFFFFu) + a4.w * bf2f(hv.y >> 16);
            }
        }
        out[n * DIM_OUT + lane] = 0.25f * acc;
    }
}

extern "C" void kernel_launch(void* const* d_in, const int* in_sizes, int n_in,
                              void* d_out, int out_size, void* d_ws, size_t ws_size,
                              hipStream_t stream) {
    const float* x  = (const float*)d_in[0];
    const int*   ei = (const int*)d_in[1];
    const float* W  = (const float*)d_in[2];
    const float* a  = (const float*)d_in[3];
    float* out = (float*)d_out;

    char* ws = (char*)d_ws;
    size_t off = 0;
    auto alloc = [&](size_t bytes) { void* p = ws + off; off = (off + bytes + 511) & ~size_t(511); return p; };
    unsigned short* h2  = (unsigned short*)alloc(sizeof(unsigned short) * N_PAD * DIM_OUT * HEADS); // 25.6 MB
    float* s_i    = (float*)alloc(sizeof(float) * N_PAD * HEADS);
    float* s_j    = (float*)alloc(sizeof(float) * N_PAD * HEADS);
    int*   bin_cursor = (int*)alloc(sizeof(int) * NBINS);                            // 6.3 KB
    unsigned int* binbuf = (unsigned int*)alloc(sizeof(unsigned int) * NBINS * CAP); // 4.4 MB
    unsigned short* Wph  = (unsigned short*)alloc(sizeof(unsigned short) * HEADS * DIM_IN * DIM_OUT); // 64 KB
    unsigned short* Wpl  = (unsigned short*)alloc(sizeof(unsigned short) * HEADS * DIM_IN * DIM_OUT); // 64 KB

    hipMemsetAsync(bin_cursor, 0, sizeof(int) * NBINS, stream);

    // pack W into MFMA fragment order (hi/lo bf16), once per launch
    pack_w_kernel<<<16, 256, 0, stream>>>(W, Wph, Wpl);

    // binning blocks [0,49) + MFMA gemm blocks [49,1612)
    fat_kernel<<<FAT_GRID, 256, 0, stream>>>(x, Wph, Wpl, a, h2, s_i, s_j, ei, bin_cursor, binbuf);

    // fused: one block per bin (LDS CSR + softmax + aggregate)
    fused_kernel<<<NBINS, 256, 0, stream>>>(bin_cursor, binbuf, s_i, s_j, h2, out);
}

// Round 14
// 188.837 us; speedup vs baseline: 1.1005x; 1.1005x over previous
//
#include <hip/hip_runtime.h>
#include <hip/hip_bf16.h>

#define N_NODES 50000
#define N_EDGES 800000
#define DIM_IN  128
#define DIM_OUT 64
#define HEADS   4
#define NEG_SLOPE 0.2f
#define NPB 32                                    // nodes per gemm block
#define GEMM_BLOCKS ((N_NODES + NPB - 1) / NPB)   // 1563
#define N_PAD (GEMM_BLOCKS * NPB)                 // 50016
#define PAD 64                                    // padded CSR slots per node (Poisson(16); guarded)
#define EPT 16                                    // edges per scatter thread
#define SCAT_THREADS (N_EDGES / EPT)              // 50000
#define SCAT_BLOCKS ((SCAT_THREADS + 255) / 256)  // 196
#define FAT_GRID (GEMM_BLOCKS + SCAT_BLOCKS)      // 1759
#define XROW 136                                  // LDS row stride (shorts) for x hi/lo
#define LTROW 260                                 // LDS row stride (shorts) for transpose buffer
#define CSTRIDE 16                                // cursor padding: one counter per 64B line
#define PREP_BLOCKS 64                            // 16 pack-W + 48 cursor-zero

typedef __attribute__((ext_vector_type(8))) short short8;
typedef __attribute__((ext_vector_type(4))) short short4v;
typedef __attribute__((ext_vector_type(4))) float f32x4;

// bf16 helpers (RNE pack, exact shift unpack)
__device__ __forceinline__ unsigned int f2bf(float f) {
    unsigned int u = __float_as_uint(f);
    return (u + 0x7FFFu + ((u >> 16) & 1u)) >> 16;
}
__device__ __forceinline__ float bf2f(unsigned int b) {
    return __uint_as_float(b << 16);
}

// ---------------- Prep: pack W into MFMA B-frag hi/lo (blocks 0-15) ---------------
//                  + zero cursor (blocks 16-63) — replaces the memset dispatch.
__global__ __launch_bounds__(256) void prep_kernel(
    const float* __restrict__ W, unsigned short* __restrict__ Wph,
    unsigned short* __restrict__ Wpl, int* __restrict__ cursor)
{
    const int b = blockIdx.x;
    const int t = threadIdx.x;
    if (b < 16) {
        const int i = b * 256 + t;                   // 0..4095 fragment-lanes
        const int lane = i & 63, nt = (i >> 6) & 3, kc = (i >> 8) & 3, h = (i >> 10) & 3;
        const int col = lane & 15, quad = lane >> 4;
        unsigned short hv[8], lv[8];
#pragma unroll
        for (int j = 0; j < 8; ++j) {
            const int k = kc * 32 + quad * 8 + j;
            const int n = nt * 16 + col;
            const float f = W[h * (DIM_IN * DIM_OUT) + k * DIM_OUT + n];
            const unsigned int hb = f2bf(f);
            hv[j] = (unsigned short)hb;
            lv[j] = (unsigned short)f2bf(f - bf2f(hb));
        }
        *(short8*)(Wph + (size_t)i * 8) = *(short8*)hv;
        *(short8*)(Wpl + (size_t)i * 8) = *(short8*)lv;
    } else {
        int4* c4 = (int4*)cursor;                    // N_NODES*CSTRIDE/4 = 200000 int4
        const int total = N_NODES * CSTRIDE / 4;
        for (int i = (b - 16) * 256 + t; i < total; i += (PREP_BLOCKS - 16) * 256)
            c4[i] = make_int4(0, 0, 0, 0);
    }
}

// ---------------- Fat kernel: MFMA-gemm blocks [0,1563) ∥ scatter [1563,1759) -----
__global__ __launch_bounds__(256) void fat_kernel(
    const float* __restrict__ x, const unsigned short* __restrict__ Wph,
    const unsigned short* __restrict__ Wpl, const float* __restrict__ a,
    unsigned short* __restrict__ h2, float* __restrict__ s_i, float* __restrict__ s_j,
    const int* __restrict__ ei, int* __restrict__ cursor, unsigned short* __restrict__ sdst)
{
    __shared__ __align__(16) unsigned char smem[2 * NPB * XROW * 2];  // 17408 B, dual-use
    const int b = blockIdx.x;
    const int t = threadIdx.x;

    if (b >= GEMM_BLOCKS) {
        // ---- scatter role: padded-CSR append, 16 edges/thread, 16 RMWs in flight
        const int i = (b - GEMM_BLOCKS) * 256 + t;
        if (i < SCAT_THREADS) {
            const int e0 = i * EPT;
            int srcs[EPT], dsts[EPT], rr[EPT];
#pragma unroll
            for (int q = 0; q < 4; ++q) {
                *(int4*)(srcs + 4 * q) = *(const int4*)(ei + e0 + 4 * q);
                *(int4*)(dsts + 4 * q) = *(const int4*)(ei + N_EDGES + e0 + 4 * q);
            }
#pragma unroll
            for (int q = 0; q < EPT; ++q)
                rr[q] = atomicAdd(&cursor[srcs[q] * CSTRIDE], 1);
#pragma unroll
            for (int q = 0; q < EPT; ++q)
                if (rr[q] < PAD) sdst[srcs[q] * PAD + rr[q]] = (unsigned short)dsts[q];
        }
        return;
    }

    // ---------------- gemm role: h = x @ W via split-bf16 MFMA ------------------
    short* xh = (short*)smem;            // [NPB][XROW]
    short* xl = xh + NPB * XROW;
    const int nb = b * NPB;

    // stage x tile as hi/lo bf16 (32 nodes x 128 dims)
    {
        const float4* xg = (const float4*)x;
        const int base = nb * (DIM_IN / 4);
        const int limit = N_NODES * (DIM_IN / 4);
#pragma unroll
        for (int r = 0; r < 4; ++r) {
            const int idx = t + 256 * r;              // 0..1023
            const int gi = base + idx;
            float4 v = {0.f, 0.f, 0.f, 0.f};
            if (gi < limit) v = xg[gi];
            const int node = idx >> 5;
            const int dg = (idx & 31) * 4;
            unsigned short hs[4], ls[4];
            const float fv[4] = {v.x, v.y, v.z, v.w};
#pragma unroll
            for (int c = 0; c < 4; ++c) {
                const unsigned int hb = f2bf(fv[c]);
                hs[c] = (unsigned short)hb;
                ls[c] = (unsigned short)f2bf(fv[c] - bf2f(hb));
            }
            *(short4v*)(xh + node * XROW + dg) = *(short4v*)hs;
            *(short4v*)(xl + node * XROW + dg) = *(short4v*)ls;
        }
    }
    __syncthreads();

    const int w = t >> 6;        // wave id == head
    const int lane = t & 63;
    const int col = lane & 15, quad = lane >> 4;

    f32x4 acc[2][4];
#pragma unroll
    for (int mt = 0; mt < 2; ++mt)
#pragma unroll
        for (int nt = 0; nt < 4; ++nt) acc[mt][nt] = (f32x4){0.f, 0.f, 0.f, 0.f};

    const short8* Bh = (const short8*)Wph;
    const short8* Bl = (const short8*)Wpl;
#pragma unroll
    for (int kc = 0; kc < 4; ++kc) {
        const short8 ah0 = *(const short8*)(xh + (0 * 16 + col) * XROW + kc * 32 + quad * 8);
        const short8 al0 = *(const short8*)(xl + (0 * 16 + col) * XROW + kc * 32 + quad * 8);
        const short8 ah1 = *(const short8*)(xh + (1 * 16 + col) * XROW + kc * 32 + quad * 8);
        const short8 al1 = *(const short8*)(xl + (1 * 16 + col) * XROW + kc * 32 + quad * 8);
#pragma unroll
        for (int nt = 0; nt < 4; ++nt) {
            const int fi = ((w * 4 + kc) * 4 + nt) * 64 + lane;
            const short8 bh = Bh[fi];
            const short8 bl = Bl[fi];
            acc[0][nt] = __builtin_amdgcn_mfma_f32_16x16x32_bf16(ah0, bh, acc[0][nt], 0, 0, 0);
            acc[0][nt] = __builtin_amdgcn_mfma_f32_16x16x32_bf16(al0, bh, acc[0][nt], 0, 0, 0);
            acc[0][nt] = __builtin_amdgcn_mfma_f32_16x16x32_bf16(ah0, bl, acc[0][nt], 0, 0, 0);
            acc[1][nt] = __builtin_amdgcn_mfma_f32_16x16x32_bf16(ah1, bh, acc[1][nt], 0, 0, 0);
            acc[1][nt] = __builtin_amdgcn_mfma_f32_16x16x32_bf16(al1, bh, acc[1][nt], 0, 0, 0);
            acc[1][nt] = __builtin_amdgcn_mfma_f32_16x16x32_bf16(ah1, bl, acc[1][nt], 0, 0, 0);
        }
    }

    // scores: lane holds h[node=mt*16+quad*4+r][head=w][o=nt*16+col]
    float aiv[4], ajv[4];
#pragma unroll
    for (int nt = 0; nt < 4; ++nt) {
        aiv[nt] = a[w * (2 * DIM_OUT) + nt * 16 + col];
        ajv[nt] = a[w * (2 * DIM_OUT) + DIM_OUT + nt * 16 + col];
    }
#pragma unroll
    for (int mt = 0; mt < 2; ++mt) {
#pragma unroll
        for (int r = 0; r < 4; ++r) {
            float pi = 0.f, pj = 0.f;
#pragma unroll
            for (int nt = 0; nt < 4; ++nt) {
                pi = fmaf(acc[mt][nt][r], aiv[nt], pi);
                pj = fmaf(acc[mt][nt][r], ajv[nt], pj);
            }
#pragma unroll
            for (int off = 8; off > 0; off >>= 1) {
                pi += __shfl_down(pi, off, 16);
                pj += __shfl_down(pj, off, 16);
            }
            if (col == 0) {
                const int n = nb + mt * 16 + quad * 4 + r;
                s_i[n * HEADS + w] = pi;
                s_j[n * HEADS + w] = pj;
            }
        }
    }
    __syncthreads();   // xh/xl consumed; smem becomes the transpose buffer

    // stage transposed bf16 tile: lt[node][o*4+head] with padded row stride
    short* lt = (short*)smem;
#pragma unroll
    for (int mt = 0; mt < 2; ++mt)
#pragma unroll
        for (int nt = 0; nt < 4; ++nt)
#pragma unroll
            for (int r = 0; r < 4; ++r)
                lt[(mt * 16 + quad * 4 + r) * LTROW + (nt * 16 + col) * 4 + w] =
                    (short)f2bf(acc[mt][nt][r]);
    __syncthreads();

    // dense write-out: 2048 uint2 = 16 KB, coalesced 8B stores
    uint2* hg = (uint2*)(h2 + (size_t)nb * (DIM_OUT * HEADS));
#pragma unroll
    for (int r = 0; r < 8; ++r) {
        const int idx = t + 256 * r;       // 0..2047
        const int node = idx >> 6;
        const int wo = idx & 63;
        hg[idx] = *(const uint2*)(lt + node * LTROW + wo * 4);
    }
}

// ---------------- Fused per-src softmax + aggregate (one wave per node) -----------
__global__ __launch_bounds__(256) void fused_kernel(
    const int* __restrict__ cursor, const unsigned short* __restrict__ sdst,
    const float* __restrict__ s_i, const float* __restrict__ s_j,
    const unsigned short* __restrict__ h2, float* __restrict__ out)
{
    __shared__ float4 att_s[4][64];
    __shared__ int    dst_s[4][64];
    const int wid = (blockIdx.x * 256 + threadIdx.x) >> 6;   // node id
    const int w = (threadIdx.x >> 6) & 3;
    const int lane = threadIdx.x & 63;
    if (wid >= N_NODES) return;
    const int n = wid;
    const int d = min(cursor[n * CSTRIDE], PAD);
    const int start = n * PAD;

    float acc = 0.f;
    if (d > 0) {
        const float4 si = *(const float4*)(s_i + n * HEADS);
        float4 m4 = {-INFINITY, -INFINITY, -INFINITY, -INFINITY};
        float4 cz = {-INFINITY, -INFINITY, -INFINITY, -INFINITY};
        int cdst = 0;
        if (lane < d) {
            cdst = (int)sdst[start + lane];
            const float4 sj = *(const float4*)(s_j + cdst * HEADS);
            float z0 = si.x + sj.x, z1 = si.y + sj.y, z2 = si.z + sj.z, z3 = si.w + sj.w;
            cz.x = z0 >= 0.f ? z0 : NEG_SLOPE * z0;
            cz.y = z1 >= 0.f ? z1 : NEG_SLOPE * z1;
            cz.z = z2 >= 0.f ? z2 : NEG_SLOPE * z2;
            cz.w = z3 >= 0.f ? z3 : NEG_SLOPE * z3;
            m4 = cz;
        }
#pragma unroll
        for (int off = 32; off > 0; off >>= 1) {
            m4.x = fmaxf(m4.x, __shfl_xor(m4.x, off, 64));
            m4.y = fmaxf(m4.y, __shfl_xor(m4.y, off, 64));
            m4.z = fmaxf(m4.z, __shfl_xor(m4.z, off, 64));
            m4.w = fmaxf(m4.w, __shfl_xor(m4.w, off, 64));
        }
        float4 ex = {0.f, 0.f, 0.f, 0.f};
        if (lane < d) {
            ex.x = __expf(cz.x - m4.x);
            ex.y = __expf(cz.y - m4.y);
            ex.z = __expf(cz.z - m4.z);
            ex.w = __expf(cz.w - m4.w);
        }
        float4 sm = ex;
#pragma unroll
        for (int off = 32; off > 0; off >>= 1) {
            sm.x += __shfl_xor(sm.x, off, 64);
            sm.y += __shfl_xor(sm.y, off, 64);
            sm.z += __shfl_xor(sm.z, off, 64);
            sm.w += __shfl_xor(sm.w, off, 64);
        }
        if (lane < d) {
            att_s[w][lane] = make_float4(ex.x / sm.x, ex.y / sm.y, ex.z / sm.z, ex.w / sm.w);
            dst_s[w][lane] = cdst;
        }

        const unsigned short* hbase = h2 + lane * HEADS;
        int e = 0;
        for (; e + 8 <= d; e += 8) {
            uint2 hv[8];
            float4 at[8];
#pragma unroll
            for (int q = 0; q < 8; ++q) {
                const int dd = dst_s[w][e + q];
                at[q] = att_s[w][e + q];
                hv[q] = *(const uint2*)(hbase + (size_t)dd * (DIM_OUT * HEADS));
            }
#pragma unroll
            for (int q = 0; q < 8; ++q) {
                acc += at[q].x * bf2f(hv[q].x & 0xFFFFu) + at[q].y * bf2f(hv[q].x >> 16)
                     + at[q].z * bf2f(hv[q].y & 0xFFFFu) + at[q].w * bf2f(hv[q].y >> 16);
            }
        }
        for (; e + 4 <= d; e += 4) {
            uint2 hv[4];
            float4 at[4];
#pragma unroll
            for (int q = 0; q < 4; ++q) {
                const int dd = dst_s[w][e + q];
                at[q] = att_s[w][e + q];
                hv[q] = *(const uint2*)(hbase + (size_t)dd * (DIM_OUT * HEADS));
            }
#pragma unroll
            for (int q = 0; q < 4; ++q) {
                acc += at[q].x * bf2f(hv[q].x & 0xFFFFu) + at[q].y * bf2f(hv[q].x >> 16)
                     + at[q].z * bf2f(hv[q].y & 0xFFFFu) + at[q].w * bf2f(hv[q].y >> 16);
            }
        }
        for (; e < d; ++e) {
            const int dd = dst_s[w][e];
            const float4 a4 = att_s[w][e];
            const uint2 hv = *(const uint2*)(hbase + (size_t)dd * (DIM_OUT * HEADS));
            acc += a4.x * bf2f(hv.x & 0xFFFFu) + a4.y * bf2f(hv.x >> 16)
                 + a4.z * bf2f(hv.y & 0xFFFFu) + a4.w * bf2f(hv.y >> 16);
        }
    }
    out[n * DIM_OUT + lane] = 0.25f * acc;
}

extern "C" void kernel_launch(void* const* d_in, const int* in_sizes, int n_in,
                              void* d_out, int out_size, void* d_ws, size_t ws_size,
                              hipStream_t stream) {
    const float* x  = (const float*)d_in[0];
    const int*   ei = (const int*)d_in[1];
    const float* W  = (const float*)d_in[2];
    const float* a  = (const float*)d_in[3];
    float* out = (float*)d_out;

    char* ws = (char*)d_ws;
    size_t off = 0;
    auto alloc = [&](size_t bytes) { void* p = ws + off; off = (off + bytes + 511) & ~size_t(511); return p; };
    unsigned short* h2  = (unsigned short*)alloc(sizeof(unsigned short) * N_PAD * DIM_OUT * HEADS); // 25.6 MB
    float* s_i    = (float*)alloc(sizeof(float) * N_PAD * HEADS);
    float* s_j    = (float*)alloc(sizeof(float) * N_PAD * HEADS);
    int*   cursor = (int*)alloc(sizeof(int) * N_NODES * CSTRIDE);   // 3.2 MB, one counter per 64B line
    unsigned short* sdst = (unsigned short*)alloc(sizeof(unsigned short) * N_NODES * PAD); // 6.4 MB
    unsigned short* Wph  = (unsigned short*)alloc(sizeof(unsigned short) * HEADS * DIM_IN * DIM_OUT); // 64 KB
    unsigned short* Wpl  = (unsigned short*)alloc(sizeof(unsigned short) * HEADS * DIM_IN * DIM_OUT); // 64 KB

    // prep: pack W (blocks 0-15) + zero cursor (blocks 16-63) — one dispatch
    prep_kernel<<<PREP_BLOCKS, 256, 0, stream>>>(W, Wph, Wpl, cursor);

    // MFMA gemm blocks [0,1563) + scatter blocks [1563,1759)
    fat_kernel<<<FAT_GRID, 256, 0, stream>>>(x, Wph, Wpl, a, h2, s_i, s_j, ei, cursor, sdst);

    // fused softmax + aggregate: one wave per node
    const int fb = (N_NODES * 64 + 255) / 256;
    fused_kernel<<<fb, 256, 0, stream>>>(cursor, sdst, s_i, s_j, h2, out);
}